// Round 1
// baseline (3405.699 us; speedup 1.0000x reference)
//
#include <hip/hip_runtime.h>
#include <math.h>

#define BB 4
#define HH 64
#define WW 64
#define CC 64
#define NN (HH*WW)          // 4096 pixels per batch
#define NPIX (BB*NN)        // 16384 total pixels
#define GROUPS 32
#define EPS 1e-3f

// ---------------- Kernel 1: GroupNorm statistics ----------------
// grid = B, block = 1024. Each thread accumulates sum/sumsq for channel (t&63).
__global__ void gn_stats(const float* __restrict__ x,
                         const float* __restrict__ gamma,
                         const float* __restrict__ beta,
                         float* __restrict__ scale,   // [B][C] : gamma*rsqrt(var+eps)
                         float* __restrict__ shift) { // [B][C] : beta - mean*scale
    int b = blockIdx.x;
    const float* xb = x + (size_t)b * NN * CC;
    int t = threadIdx.x;
    float s = 0.f, s2 = 0.f;
    for (int i = t; i < NN * CC; i += 1024) {
        float v = xb[i];
        s += v; s2 += v * v;
    }
    __shared__ float sh_s[1024];
    __shared__ float sh_s2[1024];
    sh_s[t] = s; sh_s2[t] = s2;
    __syncthreads();
    for (int stride = 512; stride >= 64; stride >>= 1) {
        if (t < stride) { sh_s[t] += sh_s[t + stride]; sh_s2[t] += sh_s2[t + stride]; }
        __syncthreads();
    }
    if (t < CC) {
        int c = t;
        int g = c >> 1;                 // 2 channels per group
        float sumg  = sh_s[g * 2]  + sh_s[g * 2 + 1];
        float sum2g = sh_s2[g * 2] + sh_s2[g * 2 + 1];
        const float n = (float)(NN * 2);
        float mean = sumg / n;
        float var  = sum2g / n - mean * mean;
        float r = rsqrtf(var + EPS);
        float a = gamma[c] * r;
        scale[b * CC + c] = a;
        shift[b * CC + c] = beta[c] - mean * a;
    }
}

// ---------------- Kernel 2: normalize + Q/K/V projections ----------------
// grid = NPIX/256, block = 256. One pixel per thread, weights staged in LDS.
__global__ void qkv_proj(const float* __restrict__ x,
                         const float* __restrict__ scale,
                         const float* __restrict__ shift,
                         const float* __restrict__ wq, const float* __restrict__ bq,
                         const float* __restrict__ wk, const float* __restrict__ bk,
                         const float* __restrict__ wv, const float* __restrict__ bv,
                         float* __restrict__ q, float* __restrict__ k,
                         float* __restrict__ v) {
    __shared__ float swq[CC * CC];
    __shared__ float swk[CC * CC];
    __shared__ float swv[CC * CC];
    int t = threadIdx.x;
    for (int i = t; i < CC * CC; i += 256) {
        swq[i] = wq[i]; swk[i] = wk[i]; swv[i] = wv[i];
    }
    __syncthreads();

    int p = blockIdx.x * 256 + t;       // global pixel id
    int b = p >> 12;                    // /4096
    const float* xp = x + (size_t)p * CC;
    const float* sc = scale + b * CC;
    const float* sf = shift + b * CC;

    float hn[CC];
    #pragma unroll
    for (int c = 0; c < CC; ++c) hn[c] = xp[c] * sc[c] + sf[c];

    float* qp = q + (size_t)p * CC;
    float* kp = k + (size_t)p * CC;
    float* vp = v + (size_t)p * CC;
    for (int d = 0; d < CC; ++d) {
        float aq = bq[d], ak = bk[d], av = bv[d];
        #pragma unroll
        for (int c = 0; c < CC; ++c) {
            float h = hn[c];
            aq += h * swq[c * CC + d];
            ak += h * swk[c * CC + d];
            av += h * swv[c * CC + d];
        }
        qp[d] = aq; kp[d] = ak; vp[d] = av;
    }
}

// ---------------- Kernel 3: full spatial attention, one query row per block ----
// grid = B*N blocks, block = 256.
__global__ void attn_row(const float* __restrict__ q,
                         const float* __restrict__ k,
                         const float* __restrict__ v,
                         float* __restrict__ o) {
    int row = blockIdx.x;               // b*4096 + i
    int b = row >> 12;
    const float* qr = q + (size_t)row * CC;
    const float* kb = k + ((size_t)b * NN) * CC;
    const float* vb = v + ((size_t)b * NN) * CC;

    __shared__ float qs[CC];
    __shared__ float p[NN];             // 16 KB score row
    __shared__ float red[256];
    __shared__ float oacc[4][CC];

    int t = threadIdx.x;
    if (t < CC) qs[t] = qr[t];
    __syncthreads();

    // scores + local max
    float lmax = -INFINITY;
    for (int j = t; j < NN; j += 256) {
        const float* kj = kb + (size_t)j * CC;
        float acc = 0.f;
        #pragma unroll
        for (int c = 0; c < CC; ++c) acc += qs[c] * kj[c];
        acc *= 0.125f;                  // * C^-0.5 = 1/8
        p[j] = acc;
        lmax = fmaxf(lmax, acc);
    }
    red[t] = lmax; __syncthreads();
    for (int s = 128; s > 0; s >>= 1) {
        if (t < s) red[t] = fmaxf(red[t], red[t + s]);
        __syncthreads();
    }
    float m = red[0];
    __syncthreads();

    // exp + sum
    float lsum = 0.f;
    for (int j = t; j < NN; j += 256) {
        float e = __expf(p[j] - m);
        p[j] = e;
        lsum += e;
    }
    red[t] = lsum; __syncthreads();
    for (int s = 128; s > 0; s >>= 1) {
        if (t < s) red[t] += red[t + s];
        __syncthreads();
    }
    float inv = 1.0f / red[0];

    // PV: thread t handles channel c = t&63 over quarter (t>>6) of the keys
    int c = t & 63, quad = t >> 6;
    float acc = 0.f;
    for (int j = quad * (NN / 4); j < (quad + 1) * (NN / 4); ++j) {
        acc += p[j] * vb[(size_t)j * CC + c];
    }
    oacc[quad][c] = acc;
    __syncthreads();
    if (t < CC) {
        float r = (oacc[0][t] + oacc[1][t] + oacc[2][t] + oacc[3][t]) * inv;
        o[(size_t)row * CC + t] = r;
    }
}

// ---------------- Kernel 4: output projection + residual ----------------
// grid = NPIX/256, block = 256. One pixel per thread.
__global__ void out_proj(const float* __restrict__ x,
                         const float* __restrict__ o,
                         const float* __restrict__ wo,
                         const float* __restrict__ bo,
                         float* __restrict__ out) {
    __shared__ float w[CC * CC];
    int t = threadIdx.x;
    for (int i = t; i < CC * CC; i += 256) w[i] = wo[i];
    __syncthreads();

    int p = blockIdx.x * 256 + t;
    const float* op = o + (size_t)p * CC;
    const float* xp = x + (size_t)p * CC;
    float* outp = out + (size_t)p * CC;

    float orow[CC];
    #pragma unroll
    for (int c = 0; c < CC; ++c) orow[c] = op[c];

    for (int d = 0; d < CC; ++d) {
        float acc = bo[d];
        #pragma unroll
        for (int c = 0; c < CC; ++c) acc += orow[c] * w[c * CC + d];
        outp[d] = xp[d] + acc;
    }
}

extern "C" void kernel_launch(void* const* d_in, const int* in_sizes, int n_in,
                              void* d_out, int out_size, void* d_ws, size_t ws_size,
                              hipStream_t stream) {
    const float* x     = (const float*)d_in[0];
    const float* gamma = (const float*)d_in[1];
    const float* beta  = (const float*)d_in[2];
    const float* wq    = (const float*)d_in[3];
    const float* bq    = (const float*)d_in[4];
    const float* wk    = (const float*)d_in[5];
    const float* bk    = (const float*)d_in[6];
    const float* wv    = (const float*)d_in[7];
    const float* bv    = (const float*)d_in[8];
    const float* wo    = (const float*)d_in[9];
    const float* bo    = (const float*)d_in[10];
    float* out = (float*)d_out;

    float* ws = (float*)d_ws;
    float* scale = ws;                      // B*C
    float* shift = scale + BB * CC;         // B*C
    float* q     = shift + BB * CC;         // NPIX*C
    float* k     = q + (size_t)NPIX * CC;
    float* v     = k + (size_t)NPIX * CC;
    float* o     = v + (size_t)NPIX * CC;

    hipLaunchKernelGGL(gn_stats, dim3(BB), dim3(1024), 0, stream,
                       x, gamma, beta, scale, shift);
    hipLaunchKernelGGL(qkv_proj, dim3(NPIX / 256), dim3(256), 0, stream,
                       x, scale, shift, wq, bq, wk, bk, wv, bv, q, k, v);
    hipLaunchKernelGGL(attn_row, dim3(BB * NN), dim3(256), 0, stream,
                       q, k, v, o);
    hipLaunchKernelGGL(out_proj, dim3(NPIX / 256), dim3(256), 0, stream,
                       x, o, wo, bo, out);
}

// Round 2
// 230.421 us; speedup vs baseline: 14.7803x; 14.7803x over previous
//
#include <hip/hip_runtime.h>
#include <math.h>

#define BB 4
#define HH 64
#define WW 64
#define CC 64
#define NN (HH*WW)          // 4096 pixels per batch
#define NPIX (BB*NN)        // 16384 total pixels
#define GROUPS 32
#define EPS 1e-3f

using bf16x8 = __attribute__((ext_vector_type(8))) short;
using f32x4  = __attribute__((ext_vector_type(4))) float;

__device__ inline unsigned short bf16bits(float f) {
    union { float f; unsigned u; } a; a.f = f;
    unsigned r = a.u + 0x7fffu + ((a.u >> 16) & 1u);   // RNE
    return (unsigned short)(r >> 16);
}
__device__ inline unsigned packbf(float lo, float hi) {
    return (unsigned)bf16bits(lo) | ((unsigned)bf16bits(hi) << 16);
}

// ---------------- Kernel 1: GroupNorm statistics ----------------
__global__ void gn_stats(const float* __restrict__ x,
                         const float* __restrict__ gamma,
                         const float* __restrict__ beta,
                         float* __restrict__ scale,
                         float* __restrict__ shift) {
    int b = blockIdx.x;
    const float* xb = x + (size_t)b * NN * CC;
    int t = threadIdx.x;
    float s = 0.f, s2 = 0.f;
    for (int i = t; i < NN * CC; i += 1024) {
        float v = xb[i];
        s += v; s2 += v * v;
    }
    __shared__ float sh_s[1024];
    __shared__ float sh_s2[1024];
    sh_s[t] = s; sh_s2[t] = s2;
    __syncthreads();
    for (int stride = 512; stride >= 64; stride >>= 1) {
        if (t < stride) { sh_s[t] += sh_s[t + stride]; sh_s2[t] += sh_s2[t + stride]; }
        __syncthreads();
    }
    if (t < CC) {
        int c = t;
        int g = c >> 1;
        float sumg  = sh_s[g * 2]  + sh_s[g * 2 + 1];
        float sum2g = sh_s2[g * 2] + sh_s2[g * 2 + 1];
        const float n = (float)(NN * 2);
        float mean = sumg / n;
        float var  = sum2g / n - mean * mean;
        float r = rsqrtf(var + EPS);
        float a = gamma[c] * r;
        scale[b * CC + c] = a;
        shift[b * CC + c] = beta[c] - mean * a;
    }
}

// ---------------- Kernel 2: normalize + QKV proj, bf16 out, V transposed ----
// grid = 256 blocks, 64 pixels/block, 4 threads per pixel (16 outputs each).
__global__ __launch_bounds__(256) void qkv_proj(
        const float* __restrict__ x,
        const float* __restrict__ scale,
        const float* __restrict__ shift,
        const float* __restrict__ wq, const float* __restrict__ bq,
        const float* __restrict__ wk, const float* __restrict__ bk,
        const float* __restrict__ wv, const float* __restrict__ bv,
        short* __restrict__ qb, short* __restrict__ kb,
        short* __restrict__ vt) {
    __shared__ float swq[CC * CC];
    __shared__ float swk[CC * CC];
    __shared__ float swv[CC * CC];
    __shared__ unsigned short vtile[64 * 74];   // padded stride 74
    int t = threadIdx.x;
    for (int i = t; i < CC * CC; i += 256) {
        swq[i] = wq[i]; swk[i] = wk[i]; swv[i] = wv[i];
    }
    __syncthreads();

    int p0 = blockIdx.x * 64;
    int p  = p0 + (t & 63);
    int qd = t >> 6;                 // 0..3
    int d0 = qd * 16;
    int bi = p >> 12;
    const float* xp = x + (size_t)p * CC;
    const float* sc = scale + bi * CC;
    const float* sf = shift + bi * CC;

    float hn[CC];
    #pragma unroll
    for (int c = 0; c < CC; ++c) hn[c] = xp[c] * sc[c] + sf[c];

    unsigned short qo[16], ko[16], vo[16];
    #pragma unroll
    for (int d = 0; d < 16; ++d) {
        float aq = bq[d0 + d], ak = bk[d0 + d], av = bv[d0 + d];
        #pragma unroll
        for (int c = 0; c < CC; ++c) {
            float h = hn[c];
            aq += h * swq[c * CC + d0 + d];
            ak += h * swk[c * CC + d0 + d];
            av += h * swv[c * CC + d0 + d];
        }
        qo[d] = bf16bits(aq * 0.125f);   // fold softmax scale into Q (exact pow2)
        ko[d] = bf16bits(ak);
        vo[d] = bf16bits(av);
    }
    // store q,k (32B per thread)
    {
        union { unsigned short u[16]; uint4 v[2]; } tq, tk;
        #pragma unroll
        for (int i = 0; i < 16; ++i) { tq.u[i] = qo[i]; tk.u[i] = ko[i]; }
        uint4* qdst = (uint4*)(qb + (size_t)p * CC + d0);
        uint4* kdst = (uint4*)(kb + (size_t)p * CC + d0);
        qdst[0] = tq.v[0]; qdst[1] = tq.v[1];
        kdst[0] = tk.v[0]; kdst[1] = tk.v[1];
    }
    // V -> LDS transpose
    #pragma unroll
    for (int d = 0; d < 16; ++d) vtile[(d0 + d) * 74 + (t & 63)] = vo[d];
    __syncthreads();
    // write vt[b][d][4096]: thread t handles row d=t>>2, 16-col segment t&3
    {
        int dd = t >> 2, seg = t & 3;
        union { unsigned short u[16]; uint4 v[2]; } tv;
        #pragma unroll
        for (int i = 0; i < 16; ++i) tv.u[i] = vtile[dd * 74 + seg * 16 + i];
        int b2 = p0 >> 12;
        uint4* dst = (uint4*)(vt + ((size_t)b2 * 64 + dd) * (size_t)NN + (p0 & (NN - 1)) + seg * 16);
        dst[0] = tv.v[0]; dst[1] = tv.v[1];
    }
}

// ---------------- Kernel 3: flash attention with MFMA ----------------
// One wave per 16 queries. 4 waves/block, grid = NPIX/64 = 256.
__global__ __launch_bounds__(256, 1) void attn_mfma(
        const short* __restrict__ qb, const short* __restrict__ kb,
        const short* __restrict__ vt, float* __restrict__ o) {
    const int lane = threadIdx.x & 63;
    const int wid  = threadIdx.x >> 6;
    const int g  = lane >> 4;
    const int cl = lane & 15;
    const int qtile = blockIdx.x * 4 + wid;      // 0..1023
    const int b  = qtile >> 8;                   // 256 q-tiles per batch
    const int q0 = (qtile & 255) << 4;
    const short* kbase = kb + ((size_t)b * NN) * CC;
    const short* vbase = vt + ((size_t)b * CC) * NN;
    const short* qbase = qb + ((size_t)b * NN + q0) * CC;

    // Q B-fragments (fixed for whole kernel): B[k][j]=Q[q0+j][k]
    bf16x8 qf0 = *(const bf16x8*)(qbase + cl * CC + g * 8);
    bf16x8 qf1 = *(const bf16x8*)(qbase + cl * CC + g * 8 + 32);

    const short* kp = kbase + cl * CC + g * 8;       // + key*64 (+32 half)
    const short* vp = vbase + cl * NN + g * 8;       // + dt*16*4096 + key

    f32x4 oacc[4];
    #pragma unroll
    for (int dt = 0; dt < 4; ++dt) oacc[dt] = (f32x4){0.f, 0.f, 0.f, 0.f};
    float m_run = -INFINITY, s_run = 0.f;

    bf16x8 kaA[8], vaA[8], kaB[8], vaB[8];

    auto loadc = [&](bf16x8 (&ka)[8], bf16x8 (&va)[8], int key0) {
        #pragma unroll
        for (int tt = 0; tt < 4; ++tt) {
            ka[2 * tt]     = *(const bf16x8*)(kp + (key0 + 16 * tt) * CC);
            ka[2 * tt + 1] = *(const bf16x8*)(kp + (key0 + 16 * tt) * CC + 32);
        }
        #pragma unroll
        for (int dt = 0; dt < 4; ++dt) {
            va[2 * dt]     = *(const bf16x8*)(vp + dt * (16 * NN) + key0);
            va[2 * dt + 1] = *(const bf16x8*)(vp + dt * (16 * NN) + key0 + 32);
        }
    };

    auto body = [&](const bf16x8 (&ka)[8], const bf16x8 (&va)[8]) {
        // S^T tiles: D = K_tile(16x32) * Q^T(32x16), accumulated over both halves
        f32x4 st[4];
        #pragma unroll
        for (int tt = 0; tt < 4; ++tt) {
            f32x4 z = (f32x4){0.f, 0.f, 0.f, 0.f};
            z = __builtin_amdgcn_mfma_f32_16x16x32_bf16(ka[2 * tt],     qf0, z, 0, 0, 0);
            z = __builtin_amdgcn_mfma_f32_16x16x32_bf16(ka[2 * tt + 1], qf1, z, 0, 0, 0);
            st[tt] = z;
        }
        // online softmax: lane holds 16 scores for query q0+cl
        float mx = -INFINITY;
        #pragma unroll
        for (int tt = 0; tt < 4; ++tt) {
            mx = fmaxf(mx, fmaxf(fmaxf(st[tt][0], st[tt][1]), fmaxf(st[tt][2], st[tt][3])));
        }
        mx = fmaxf(mx, __shfl_xor(mx, 16));
        mx = fmaxf(mx, __shfl_xor(mx, 32));
        float mnew = fmaxf(m_run, mx);
        float fold = __expf(m_run - mnew);
        float psum = 0.f;
        unsigned pk[4][2];
        #pragma unroll
        for (int tt = 0; tt < 4; ++tt) {
            float p0v = __expf(st[tt][0] - mnew);
            float p1v = __expf(st[tt][1] - mnew);
            float p2v = __expf(st[tt][2] - mnew);
            float p3v = __expf(st[tt][3] - mnew);
            psum += (p0v + p1v) + (p2v + p3v);
            pk[tt][0] = packbf(p0v, p1v);
            pk[tt][1] = packbf(p2v, p3v);
        }
        psum += __shfl_xor(psum, 16);
        psum += __shfl_xor(psum, 32);
        s_run = s_run * fold + psum;
        m_run = mnew;
        // rescale O: factor for row 4g+r lives at lane 4g+r (its cl == 4g+r)
        float fr[4];
        #pragma unroll
        for (int r = 0; r < 4; ++r) fr[r] = __shfl(fold, 4 * g + r);
        #pragma unroll
        for (int dt = 0; dt < 4; ++dt) {
            #pragma unroll
            for (int r = 0; r < 4; ++r) oacc[dt][r] *= fr[r];
        }
        // build P A-fragments (keys 32kc..32kc+31) and do PV
        #pragma unroll
        for (int kc = 0; kc < 2; ++kc) {
            union { bf16x8 v; unsigned u[4]; } pa;
            #pragma unroll
            for (int r = 0; r < 4; ++r) {
                int srcl = ((2 * g + (r >> 1)) & 3) * 16 + cl;
                unsigned lo = __shfl(pk[2 * kc][r & 1], srcl);
                unsigned hi = __shfl(pk[2 * kc + 1][r & 1], srcl);
                pa.u[r] = (g >= 2) ? hi : lo;
            }
            #pragma unroll
            for (int dt = 0; dt < 4; ++dt)
                oacc[dt] = __builtin_amdgcn_mfma_f32_16x16x32_bf16(pa.v, va[2 * dt + kc], oacc[dt], 0, 0, 0);
        }
    };

    loadc(kaA, vaA, 0);
    for (int chunk = 0; chunk < 64; chunk += 2) {
        if (chunk + 1 < 64) loadc(kaB, vaB, (chunk + 1) * 64);
        body(kaA, vaA);
        if (chunk + 2 < 64) loadc(kaA, vaA, (chunk + 2) * 64);
        body(kaB, vaB);
    }

    float inv = 1.f / s_run;
    float ir[4];
    #pragma unroll
    for (int r = 0; r < 4; ++r) ir[r] = __shfl(inv, 4 * g + r);
    float* ob = o + ((size_t)b * NN + q0) * CC;
    #pragma unroll
    for (int dt = 0; dt < 4; ++dt) {
        #pragma unroll
        for (int r = 0; r < 4; ++r)
            ob[(4 * g + r) * CC + dt * 16 + cl] = oacc[dt][r] * ir[r];
    }
}

// ---------------- Kernel 4: output projection + residual ----------------
// grid = 256 blocks, 64 pixels/block, 4 threads per pixel.
__global__ __launch_bounds__(256) void out_proj(
        const float* __restrict__ x,
        const float* __restrict__ o,
        const float* __restrict__ wo,
        const float* __restrict__ bo,
        float* __restrict__ out) {
    __shared__ float w[CC * CC];
    int t = threadIdx.x;
    for (int i = t; i < CC * CC; i += 256) w[i] = wo[i];
    __syncthreads();

    int p  = blockIdx.x * 64 + (t & 63);
    int d0 = (t >> 6) * 16;
    const float* op = o + (size_t)p * CC;
    float orow[CC];
    #pragma unroll
    for (int c = 0; c < CC; ++c) orow[c] = op[c];

    #pragma unroll
    for (int d = 0; d < 16; ++d) {
        float acc = bo[d0 + d];
        #pragma unroll
        for (int c = 0; c < CC; ++c) acc += orow[c] * w[c * CC + d0 + d];
        out[(size_t)p * CC + d0 + d] = x[(size_t)p * CC + d0 + d] + acc;
    }
}

extern "C" void kernel_launch(void* const* d_in, const int* in_sizes, int n_in,
                              void* d_out, int out_size, void* d_ws, size_t ws_size,
                              hipStream_t stream) {
    const float* x     = (const float*)d_in[0];
    const float* gamma = (const float*)d_in[1];
    const float* beta  = (const float*)d_in[2];
    const float* wq    = (const float*)d_in[3];
    const float* bq    = (const float*)d_in[4];
    const float* wk    = (const float*)d_in[5];
    const float* bk    = (const float*)d_in[6];
    const float* wv    = (const float*)d_in[7];
    const float* bv    = (const float*)d_in[8];
    const float* wo    = (const float*)d_in[9];
    const float* bo    = (const float*)d_in[10];
    float* out = (float*)d_out;

    float* ws    = (float*)d_ws;
    float* scale = ws;                                  // 256
    float* shift = scale + BB * CC;                     // 256
    short* qb    = (short*)(shift + BB * CC);           // NPIX*CC bf16
    short* kbp   = qb  + (size_t)NPIX * CC;
    short* vtp   = kbp + (size_t)NPIX * CC;
    float* o     = (float*)(vtp + (size_t)NPIX * CC);   // NPIX*CC f32

    hipLaunchKernelGGL(gn_stats, dim3(BB), dim3(1024), 0, stream,
                       x, gamma, beta, scale, shift);
    hipLaunchKernelGGL(qkv_proj, dim3(NPIX / 64), dim3(256), 0, stream,
                       x, scale, shift, wq, bq, wk, bk, wv, bv, qb, kbp, vtp);
    hipLaunchKernelGGL(attn_mfma, dim3(NPIX / 64), dim3(256), 0, stream,
                       qb, kbp, vtp, o);
    hipLaunchKernelGGL(out_proj, dim3(NPIX / 64), dim3(256), 0, stream,
                       x, o, wo, bo, out);
}

// Round 3
// 141.392 us; speedup vs baseline: 24.0870x; 1.6297x over previous
//
#include <hip/hip_runtime.h>
#include <math.h>

#define BB 4
#define HH 64
#define WW 64
#define CC 64
#define NN (HH*WW)          // 4096 pixels per batch
#define NPIX (BB*NN)        // 16384 total pixels
#define EPS 1e-3f
#define KSPLIT 4
#define NQT (NPIX/16)       // 1024 query tiles of 16

using bf16x8 = __attribute__((ext_vector_type(8))) short;
using f32x4  = __attribute__((ext_vector_type(4))) float;

__device__ inline unsigned short bf16bits(float f) {
    union { float f; unsigned u; } a; a.f = f;
    unsigned r = a.u + 0x7fffu + ((a.u >> 16) & 1u);   // RNE
    return (unsigned short)(r >> 16);
}
__device__ inline unsigned packbf(float lo, float hi) {
    return (unsigned)bf16bits(lo) | ((unsigned)bf16bits(hi) << 16);
}

// ---------------- Kernel 1a: GroupNorm partial sums ----------------
// grid 256, block 256. Block handles 64 pixels; partial per-channel sums.
__global__ __launch_bounds__(256) void gn_partial(const float* __restrict__ x,
                                                  float* __restrict__ part) {
    int t = threadIdx.x;
    int c = t & 63, rr = t >> 6;
    int p0 = blockIdx.x * 64;
    float s = 0.f, s2 = 0.f;
    #pragma unroll
    for (int k = 0; k < 16; ++k) {
        float v = x[(size_t)(p0 + rr + 4 * k) * CC + c];
        s += v; s2 += v * v;
    }
    __shared__ float sA[256], sB[256];
    sA[t] = s; sB[t] = s2;
    __syncthreads();
    if (t < 64) {
        float fs  = sA[t] + sA[64 + t] + sA[128 + t] + sA[192 + t];
        float fs2 = sB[t] + sB[64 + t] + sB[128 + t] + sB[192 + t];
        part[blockIdx.x * 128 + t]      = fs;
        part[blockIdx.x * 128 + 64 + t] = fs2;
    }
}

// ---------------- Kernel 1b: GroupNorm finalize ----------------
// grid 4 (batch), block 256.
__global__ __launch_bounds__(256) void gn_final(const float* __restrict__ part,
                                                const float* __restrict__ gamma,
                                                const float* __restrict__ beta,
                                                float* __restrict__ scale,
                                                float* __restrict__ shift) {
    int b = blockIdx.x;
    int t = threadIdx.x;
    int c = t & 63, rr = t >> 6;
    float s = 0.f, s2 = 0.f;
    #pragma unroll
    for (int k = 0; k < 16; ++k) {
        int blk = b * 64 + rr + 4 * k;
        s  += part[blk * 128 + c];
        s2 += part[blk * 128 + 64 + c];
    }
    __shared__ float sA[256], sB[256];
    sA[t] = s; sB[t] = s2;
    __syncthreads();
    if (t < 64) {
        sA[t] = sA[t] + sA[64 + t] + sA[128 + t] + sA[192 + t];
        sB[t] = sB[t] + sB[64 + t] + sB[128 + t] + sB[192 + t];
    }
    __syncthreads();
    if (t < 64) {
        int g = t >> 1;
        float sumg  = sA[g * 2] + sA[g * 2 + 1];
        float sum2g = sB[g * 2] + sB[g * 2 + 1];
        const float n = (float)(NN * 2);
        float mean = sumg / n;
        float var  = sum2g / n - mean * mean;
        float r = rsqrtf(var + EPS);
        float a = gamma[t] * r;
        scale[b * CC + t] = a;
        shift[b * CC + t] = beta[t] - mean * a;
    }
}

// ---------------- Kernel 2: weight transpose into MFMA B-fragment layout ----
// wfrag[m][dt][h][lane][8] bf16; element = w_m[(h*32+g*8+j)*64 + dt*16+cl]
__global__ __launch_bounds__(256) void wt_prep(const float* __restrict__ wq,
                                               const float* __restrict__ wk,
                                               const float* __restrict__ wv,
                                               const float* __restrict__ wo,
                                               short* __restrict__ wfrag) {
    const float* mats[4] = {wq, wk, wv, wo};
    int i0 = blockIdx.x * 256 + threadIdx.x;
    for (int e = i0; e < 16384; e += 16 * 256) {
        int m = e >> 12;
        int r = e & 4095;
        int dt = r >> 10, h = (r >> 9) & 1, lane = (r >> 3) & 63, j = r & 7;
        int g = lane >> 4, cl = lane & 15;
        float v = mats[m][(h * 32 + g * 8 + j) * 64 + dt * 16 + cl];
        wfrag[e] = (short)bf16bits(v);
    }
}

// ---------------- Kernel 3: normalize + QKV proj via MFMA ----------------
// grid 256, block 256 (4 waves). Wave handles 16 pixels.
__global__ __launch_bounds__(256) void qkv_proj(
        const float* __restrict__ x,
        const float* __restrict__ scale,
        const float* __restrict__ shift,
        const short* __restrict__ wfrag,
        const float* __restrict__ bq, const float* __restrict__ bk,
        const float* __restrict__ bv,
        short* __restrict__ qb, short* __restrict__ kb,
        short* __restrict__ vt) {
    __shared__ unsigned short vtile[64 * 72];
    int t = threadIdx.x;
    int lane = t & 63, wid = t >> 6;
    int g = lane >> 4, cl = lane & 15;
    int pixblk = blockIdx.x * 64;
    int pix0 = pixblk + wid * 16;
    int b = pixblk >> 12;

    // A-fragments: hn rows for 16 pixels
    const float* xp = x + (size_t)(pix0 + cl) * CC + g * 8;
    float4 x00 = *(const float4*)(xp);
    float4 x01 = *(const float4*)(xp + 4);
    float4 x10 = *(const float4*)(xp + 32);
    float4 x11 = *(const float4*)(xp + 36);
    const float* scb = scale + b * CC + g * 8;
    const float* sfb = shift + b * CC + g * 8;
    float4 s00 = *(const float4*)(scb);
    float4 s01 = *(const float4*)(scb + 4);
    float4 s10 = *(const float4*)(scb + 32);
    float4 s11 = *(const float4*)(scb + 36);
    float4 f00 = *(const float4*)(sfb);
    float4 f01 = *(const float4*)(sfb + 4);
    float4 f10 = *(const float4*)(sfb + 32);
    float4 f11 = *(const float4*)(sfb + 36);

    union { bf16x8 v; unsigned u[4]; } af0, af1;
    af0.u[0] = packbf(x00.x * s00.x + f00.x, x00.y * s00.y + f00.y);
    af0.u[1] = packbf(x00.z * s00.z + f00.z, x00.w * s00.w + f00.w);
    af0.u[2] = packbf(x01.x * s01.x + f01.x, x01.y * s01.y + f01.y);
    af0.u[3] = packbf(x01.z * s01.z + f01.z, x01.w * s01.w + f01.w);
    af1.u[0] = packbf(x10.x * s10.x + f10.x, x10.y * s10.y + f10.y);
    af1.u[1] = packbf(x10.z * s10.z + f10.z, x10.w * s10.w + f10.w);
    af1.u[2] = packbf(x11.x * s11.x + f11.x, x11.y * s11.y + f11.y);
    af1.u[3] = packbf(x11.z * s11.z + f11.z, x11.w * s11.w + f11.w);

    // 3 matrices x 4 d-tiles
    #pragma unroll
    for (int m = 0; m < 3; ++m) {
        const float* bias = (m == 0) ? bq : (m == 1) ? bk : bv;
        #pragma unroll
        for (int dt = 0; dt < 4; ++dt) {
            bf16x8 w0 = *(const bf16x8*)(wfrag + (size_t)(((m * 4 + dt) * 2 + 0) * 64 + lane) * 8);
            bf16x8 w1 = *(const bf16x8*)(wfrag + (size_t)(((m * 4 + dt) * 2 + 1) * 64 + lane) * 8);
            f32x4 z = (f32x4){0.f, 0.f, 0.f, 0.f};
            z = __builtin_amdgcn_mfma_f32_16x16x32_bf16(af0.v, w0, z, 0, 0, 0);
            z = __builtin_amdgcn_mfma_f32_16x16x32_bf16(af1.v, w1, z, 0, 0, 0);
            float bias_d = bias[dt * 16 + cl];
            if (m == 0) {
                #pragma unroll
                for (int r = 0; r < 4; ++r)
                    qb[(size_t)(pix0 + 4 * g + r) * CC + dt * 16 + cl] =
                        (short)bf16bits((z[r] + bias_d) * 0.125f);
            } else if (m == 1) {
                #pragma unroll
                for (int r = 0; r < 4; ++r)
                    kb[(size_t)(pix0 + 4 * g + r) * CC + dt * 16 + cl] =
                        (short)bf16bits(z[r] + bias_d);
            } else {
                #pragma unroll
                for (int r = 0; r < 4; ++r)
                    vtile[(dt * 16 + cl) * 72 + wid * 16 + 4 * g + r] =
                        bf16bits(z[r] + bias_d);
            }
        }
    }
    __syncthreads();
    // vectorized V^T store: thread t -> d = t>>2, 16-pixel segment t&3
    {
        int d = t >> 2, seg = t & 3;
        uint4 v0 = *(const uint4*)(vtile + d * 72 + seg * 16);
        uint4 v1 = *(const uint4*)(vtile + d * 72 + seg * 16 + 8);
        uint4* dst = (uint4*)(vt + ((size_t)(b * 64 + d)) * NN + pixblk + seg * 16);
        dst[0] = v0; dst[1] = v1;
    }
}

// ---------------- Kernel 4: flash attention, split-K, partial outputs ------
// grid 1024 blocks x 4 waves. kseg = blockIdx>>8 shared per block (L1 reuse).
__global__ __launch_bounds__(256, 1) void attn_mfma(
        const short* __restrict__ qb, const short* __restrict__ kb,
        const short* __restrict__ vt,
        float* __restrict__ obuf, float* __restrict__ msbuf) {
    const int lane = threadIdx.x & 63;
    const int wid  = threadIdx.x >> 6;
    const int g  = lane >> 4;
    const int cl = lane & 15;
    const int kseg = blockIdx.x >> 8;
    const int qtile = (blockIdx.x & 255) * 4 + wid;   // 0..1023
    const int b  = qtile >> 8;
    const int q0 = (qtile & 255) << 4;
    const int kbase0 = kseg * (NN / KSPLIT);          // 1024-key window
    const short* kbase = kb + ((size_t)b * NN) * CC;
    const short* vbase = vt + ((size_t)b * CC) * NN;
    const short* qbase = qb + ((size_t)b * NN + q0) * CC;

    bf16x8 qf0 = *(const bf16x8*)(qbase + cl * CC + g * 8);
    bf16x8 qf1 = *(const bf16x8*)(qbase + cl * CC + g * 8 + 32);

    const short* kp = kbase + cl * CC + g * 8;
    const short* vp = vbase + cl * NN + g * 8;

    f32x4 oacc[4];
    #pragma unroll
    for (int dt = 0; dt < 4; ++dt) oacc[dt] = (f32x4){0.f, 0.f, 0.f, 0.f};
    float m_run = -INFINITY, s_run = 0.f;

    bf16x8 kaA[8], vaA[8], kaB[8], vaB[8];

    auto loadc = [&](bf16x8 (&ka)[8], bf16x8 (&va)[8], int key0) {
        #pragma unroll
        for (int tt = 0; tt < 4; ++tt) {
            ka[2 * tt]     = *(const bf16x8*)(kp + (size_t)(key0 + 16 * tt) * CC);
            ka[2 * tt + 1] = *(const bf16x8*)(kp + (size_t)(key0 + 16 * tt) * CC + 32);
        }
        #pragma unroll
        for (int dt = 0; dt < 4; ++dt) {
            va[2 * dt]     = *(const bf16x8*)(vp + (size_t)dt * (16 * NN) + key0);
            va[2 * dt + 1] = *(const bf16x8*)(vp + (size_t)dt * (16 * NN) + key0 + 32);
        }
    };

    auto body = [&](const bf16x8 (&ka)[8], const bf16x8 (&va)[8]) {
        f32x4 st[4];
        #pragma unroll
        for (int tt = 0; tt < 4; ++tt) {
            f32x4 z = (f32x4){0.f, 0.f, 0.f, 0.f};
            z = __builtin_amdgcn_mfma_f32_16x16x32_bf16(ka[2 * tt],     qf0, z, 0, 0, 0);
            z = __builtin_amdgcn_mfma_f32_16x16x32_bf16(ka[2 * tt + 1], qf1, z, 0, 0, 0);
            st[tt] = z;
        }
        float mx = -INFINITY;
        #pragma unroll
        for (int tt = 0; tt < 4; ++tt)
            mx = fmaxf(mx, fmaxf(fmaxf(st[tt][0], st[tt][1]), fmaxf(st[tt][2], st[tt][3])));
        mx = fmaxf(mx, __shfl_xor(mx, 16));
        mx = fmaxf(mx, __shfl_xor(mx, 32));
        float mnew = fmaxf(m_run, mx);
        float fold = __expf(m_run - mnew);
        float psum = 0.f;
        unsigned pk[4][2];
        #pragma unroll
        for (int tt = 0; tt < 4; ++tt) {
            float p0v = __expf(st[tt][0] - mnew);
            float p1v = __expf(st[tt][1] - mnew);
            float p2v = __expf(st[tt][2] - mnew);
            float p3v = __expf(st[tt][3] - mnew);
            psum += (p0v + p1v) + (p2v + p3v);
            pk[tt][0] = packbf(p0v, p1v);
            pk[tt][1] = packbf(p2v, p3v);
        }
        psum += __shfl_xor(psum, 16);
        psum += __shfl_xor(psum, 32);
        s_run = s_run * fold + psum;
        m_run = mnew;
        float fr[4];
        #pragma unroll
        for (int r = 0; r < 4; ++r) fr[r] = __shfl(fold, 4 * g + r);
        #pragma unroll
        for (int dt = 0; dt < 4; ++dt) {
            #pragma unroll
            for (int r = 0; r < 4; ++r) oacc[dt][r] *= fr[r];
        }
        #pragma unroll
        for (int kc = 0; kc < 2; ++kc) {
            union { bf16x8 v; unsigned u[4]; } pa;
            #pragma unroll
            for (int r = 0; r < 4; ++r) {
                int srcl = ((2 * g + (r >> 1)) & 3) * 16 + cl;
                unsigned lo = __shfl(pk[2 * kc][r & 1], srcl);
                unsigned hi = __shfl(pk[2 * kc + 1][r & 1], srcl);
                pa.u[r] = (g >= 2) ? hi : lo;
            }
            #pragma unroll
            for (int dt = 0; dt < 4; ++dt)
                oacc[dt] = __builtin_amdgcn_mfma_f32_16x16x32_bf16(pa.v, va[2 * dt + kc], oacc[dt], 0, 0, 0);
        }
    };

    loadc(kaA, vaA, kbase0);
    #pragma unroll 1
    for (int chunk = 0; chunk < 16; chunk += 2) {
        loadc(kaB, vaB, kbase0 + (chunk + 1) * 64);
        body(kaA, vaA);
        if (chunk + 2 < 16) loadc(kaA, vaA, kbase0 + (chunk + 2) * 64);
        body(kaB, vaB);
    }

    // store partial (unnormalized) O and per-query (m, s)
    int task = qtile * KSPLIT + kseg;
    float* ob = obuf + (size_t)task * 1024;
    #pragma unroll
    for (int dt = 0; dt < 4; ++dt) {
        #pragma unroll
        for (int r = 0; r < 4; ++r)
            ob[(4 * g + r) * CC + dt * 16 + cl] = oacc[dt][r];
    }
    if (lane < 16) {
        msbuf[task * 32 + lane * 2]     = m_run;
        msbuf[task * 32 + lane * 2 + 1] = s_run;
    }
}

// ---------------- Kernel 5: merge split-K partials + out-proj + residual ----
// grid 256, block 256 (4 waves). Wave handles one qtile (16 pixels).
__global__ __launch_bounds__(256) void attn_merge_outproj(
        const float* __restrict__ obuf, const float* __restrict__ msbuf,
        const short* __restrict__ wfrag,
        const float* __restrict__ x,
        const float* __restrict__ bo,
        float* __restrict__ out) {
    int t = threadIdx.x;
    int lane = t & 63, wid = t >> 6;
    int g = lane >> 4, cl = lane & 15;
    int qtile = blockIdx.x * 4 + wid;

    // per-row merge coefficients (row = cl)
    float m_s[KSPLIT], s_s[KSPLIT];
    #pragma unroll
    for (int s = 0; s < KSPLIT; ++s) {
        m_s[s] = msbuf[(qtile * KSPLIT + s) * 32 + cl * 2];
        s_s[s] = msbuf[(qtile * KSPLIT + s) * 32 + cl * 2 + 1];
    }
    float mstar = fmaxf(fmaxf(m_s[0], m_s[1]), fmaxf(m_s[2], m_s[3]));
    float wgt[KSPLIT], stot = 0.f;
    #pragma unroll
    for (int s = 0; s < KSPLIT; ++s) {
        wgt[s] = __expf(m_s[s] - mstar);
        stot += wgt[s] * s_s[s];
    }
    float invs = 1.f / stot;
    #pragma unroll
    for (int s = 0; s < KSPLIT; ++s) wgt[s] *= invs;

    // merge O: lane (g,cl) holds o[row=cl][ch = h*32 + g*8 + j]
    float ov[2][8];
    #pragma unroll
    for (int h = 0; h < 2; ++h) {
        #pragma unroll
        for (int j = 0; j < 8; ++j) ov[h][j] = 0.f;
        #pragma unroll
        for (int s = 0; s < KSPLIT; ++s) {
            const float* ob = obuf + (size_t)(qtile * KSPLIT + s) * 1024 + cl * CC + h * 32 + g * 8;
            float4 a0 = *(const float4*)(ob);
            float4 a1 = *(const float4*)(ob + 4);
            float w = wgt[s];
            ov[h][0] += w * a0.x; ov[h][1] += w * a0.y;
            ov[h][2] += w * a0.z; ov[h][3] += w * a0.w;
            ov[h][4] += w * a1.x; ov[h][5] += w * a1.y;
            ov[h][6] += w * a1.z; ov[h][7] += w * a1.w;
        }
    }
    union { bf16x8 v; unsigned u[4]; } af0, af1;
    #pragma unroll
    for (int p = 0; p < 4; ++p) {
        af0.u[p] = packbf(ov[0][2 * p], ov[0][2 * p + 1]);
        af1.u[p] = packbf(ov[1][2 * p], ov[1][2 * p + 1]);
    }

    // out-proj (m=3 fragments) + bias + residual
    #pragma unroll
    for (int dt = 0; dt < 4; ++dt) {
        bf16x8 w0 = *(const bf16x8*)(wfrag + (size_t)(((3 * 4 + dt) * 2 + 0) * 64 + lane) * 8);
        bf16x8 w1 = *(const bf16x8*)(wfrag + (size_t)(((3 * 4 + dt) * 2 + 1) * 64 + lane) * 8);
        f32x4 z = (f32x4){0.f, 0.f, 0.f, 0.f};
        z = __builtin_amdgcn_mfma_f32_16x16x32_bf16(af0.v, w0, z, 0, 0, 0);
        z = __builtin_amdgcn_mfma_f32_16x16x32_bf16(af1.v, w1, z, 0, 0, 0);
        float bias_d = bo[dt * 16 + cl];
        #pragma unroll
        for (int r = 0; r < 4; ++r) {
            size_t idx = (size_t)(qtile * 16 + 4 * g + r) * CC + dt * 16 + cl;
            out[idx] = x[idx] + z[r] + bias_d;
        }
    }
}

extern "C" void kernel_launch(void* const* d_in, const int* in_sizes, int n_in,
                              void* d_out, int out_size, void* d_ws, size_t ws_size,
                              hipStream_t stream) {
    const float* x     = (const float*)d_in[0];
    const float* gamma = (const float*)d_in[1];
    const float* beta  = (const float*)d_in[2];
    const float* wq    = (const float*)d_in[3];
    const float* bq    = (const float*)d_in[4];
    const float* wk    = (const float*)d_in[5];
    const float* bk    = (const float*)d_in[6];
    const float* wv    = (const float*)d_in[7];
    const float* bv    = (const float*)d_in[8];
    const float* wo    = (const float*)d_in[9];
    const float* bo    = (const float*)d_in[10];
    float* out = (float*)d_out;

    float* ws    = (float*)d_ws;
    float* scale = ws;                                   // 256
    float* shift = scale + 256;                          // 256
    float* part  = shift + 256;                          // 256*128
    short* wfrag = (short*)(part + 256 * 128);           // 16384 bf16
    short* qb    = wfrag + 16384;                        // NPIX*64 bf16
    short* kbp   = qb  + (size_t)NPIX * CC;
    short* vtp   = kbp + (size_t)NPIX * CC;
    float* obuf  = (float*)(vtp + (size_t)NPIX * CC);    // NQT*KSPLIT*1024 f32
    float* msbuf = obuf + (size_t)NQT * KSPLIT * 1024;   // NQT*KSPLIT*32 f32

    hipLaunchKernelGGL(wt_prep, dim3(16), dim3(256), 0, stream,
                       wq, wk, wv, wo, wfrag);
    hipLaunchKernelGGL(gn_partial, dim3(256), dim3(256), 0, stream, x, part);
    hipLaunchKernelGGL(gn_final, dim3(BB), dim3(256), 0, stream,
                       part, gamma, beta, scale, shift);
    hipLaunchKernelGGL(qkv_proj, dim3(256), dim3(256), 0, stream,
                       x, scale, shift, wfrag, bq, bk, bv, qb, kbp, vtp);
    hipLaunchKernelGGL(attn_mfma, dim3(NQT), dim3(256), 0, stream,
                       qb, kbp, vtp, obuf, msbuf);
    hipLaunchKernelGGL(attn_merge_outproj, dim3(256), dim3(256), 0, stream,
                       obuf, msbuf, wfrag, x, bo, out);
}

// Round 4
// 90.263 us; speedup vs baseline: 37.7310x; 1.5664x over previous
//
#include <hip/hip_runtime.h>
#include <math.h>

#define BB 4
#define HH 64
#define WW 64
#define CC 64
#define NN (HH*WW)          // 4096 pixels per batch
#define NPIX (BB*NN)        // 16384 total pixels
#define EPS 1e-3f
#define KSPLIT 8
#define QBLK 32
#define NQT32 (NPIX/QBLK)   // 512 query tiles of 32

using bf16x8 = __attribute__((ext_vector_type(8))) short;
using f32x4  = __attribute__((ext_vector_type(4))) float;
using f32x16 = __attribute__((ext_vector_type(16))) float;

__device__ inline unsigned short bf16bits(float f) {
    union { float f; unsigned u; } a; a.f = f;
    unsigned r = a.u + 0x7fffu + ((a.u >> 16) & 1u);   // RNE
    return (unsigned short)(r >> 16);
}
__device__ inline unsigned packbf(float lo, float hi) {
    return (unsigned)bf16bits(lo) | ((unsigned)bf16bits(hi) << 16);
}
__device__ inline unsigned cvtpk(float lo, float hi) {
    unsigned r;
    asm("v_cvt_pk_bf16_f32 %0, %1, %2" : "=v"(r) : "v"(lo), "v"(hi));
    return r;
}
#define PSWAP(a, b) asm("v_permlane32_swap_b32 %0, %1" : "+v"(a), "+v"(b))

__device__ inline float bf2f(unsigned short u) {
    union { unsigned u; float f; } a; a.u = ((unsigned)u) << 16;
    return a.f;
}

// ---------------- Kernel 1a: GroupNorm partial sums ----------------
__global__ __launch_bounds__(256) void gn_partial(const float* __restrict__ x,
                                                  float* __restrict__ part) {
    int t = threadIdx.x;
    int c = t & 63, rr = t >> 6;
    int p0 = blockIdx.x * 64;
    float s = 0.f, s2 = 0.f;
    #pragma unroll
    for (int k = 0; k < 16; ++k) {
        float v = x[(size_t)(p0 + rr + 4 * k) * CC + c];
        s += v; s2 += v * v;
    }
    __shared__ float sA[256], sB[256];
    sA[t] = s; sB[t] = s2;
    __syncthreads();
    if (t < 64) {
        float fs  = sA[t] + sA[64 + t] + sA[128 + t] + sA[192 + t];
        float fs2 = sB[t] + sB[64 + t] + sB[128 + t] + sB[192 + t];
        part[blockIdx.x * 128 + t]      = fs;
        part[blockIdx.x * 128 + 64 + t] = fs2;
    }
}

// ---------------- Kernel 1b: GroupNorm finalize ----------------
__global__ __launch_bounds__(256) void gn_final(const float* __restrict__ part,
                                                const float* __restrict__ gamma,
                                                const float* __restrict__ beta,
                                                float* __restrict__ scale,
                                                float* __restrict__ shift) {
    int b = blockIdx.x;
    int t = threadIdx.x;
    int c = t & 63, rr = t >> 6;
    float s = 0.f, s2 = 0.f;
    #pragma unroll
    for (int k = 0; k < 16; ++k) {
        int blk = b * 64 + rr + 4 * k;
        s  += part[blk * 128 + c];
        s2 += part[blk * 128 + 64 + c];
    }
    __shared__ float sA[256], sB[256];
    sA[t] = s; sB[t] = s2;
    __syncthreads();
    if (t < 64) {
        sA[t] = sA[t] + sA[64 + t] + sA[128 + t] + sA[192 + t];
        sB[t] = sB[t] + sB[64 + t] + sB[128 + t] + sB[192 + t];
    }
    __syncthreads();
    if (t < 64) {
        int g = t >> 1;
        float sumg  = sA[g * 2] + sA[g * 2 + 1];
        float sum2g = sB[g * 2] + sB[g * 2 + 1];
        const float n = (float)(NN * 2);
        float mean = sumg / n;
        float var  = sum2g / n - mean * mean;
        float r = rsqrtf(var + EPS);
        float a = gamma[t] * r;
        scale[b * CC + t] = a;
        shift[b * CC + t] = beta[t] - mean * a;
    }
}

// ---------------- Kernel 2: weight prep ----------------
// region 1 (12288): q/k/v 16x16 B-frag layout (as before, m=0..2)
// region 2 (4096):  wo 32x32 B-frag layout: [s][dt][lane][j]
__global__ __launch_bounds__(256) void wt_prep(const float* __restrict__ wq,
                                               const float* __restrict__ wk,
                                               const float* __restrict__ wv,
                                               const float* __restrict__ wo,
                                               short* __restrict__ wfrag) {
    const float* mats[3] = {wq, wk, wv};
    int i0 = blockIdx.x * 256 + threadIdx.x;
    for (int e = i0; e < 12288; e += 16 * 256) {
        int m = e >> 12;
        int r = e & 4095;
        int dt = r >> 10, h = (r >> 9) & 1, lane = (r >> 3) & 63, j = r & 7;
        int g = lane >> 4, cl = lane & 15;
        float v = mats[m][(h * 32 + g * 8 + j) * 64 + dt * 16 + cl];
        wfrag[e] = (short)bf16bits(v);
    }
    for (int e = i0; e < 4096; e += 16 * 256) {
        int j = e & 7, lane = (e >> 3) & 63, dt = (e >> 9) & 1, s = e >> 10;
        int hi = lane >> 5, l31 = lane & 31;
        float v = wo[(8 * hi + 16 * s + j) * 64 + dt * 32 + l31];
        wfrag[12288 + e] = (short)bf16bits(v);
    }
}

// ---------------- Kernel 3: normalize + QKV proj via MFMA (16x16) --------
__global__ __launch_bounds__(256) void qkv_proj(
        const float* __restrict__ x,
        const float* __restrict__ scale,
        const float* __restrict__ shift,
        const short* __restrict__ wfrag,
        const float* __restrict__ bq, const float* __restrict__ bk,
        const float* __restrict__ bv,
        short* __restrict__ qb, short* __restrict__ kb,
        short* __restrict__ vt) {
    __shared__ unsigned short vtile[64 * 72];
    int t = threadIdx.x;
    int lane = t & 63, wid = t >> 6;
    int g = lane >> 4, cl = lane & 15;
    int pixblk = blockIdx.x * 64;
    int pix0 = pixblk + wid * 16;
    int b = pixblk >> 12;

    const float* xp = x + (size_t)(pix0 + cl) * CC + g * 8;
    float4 x00 = *(const float4*)(xp);
    float4 x01 = *(const float4*)(xp + 4);
    float4 x10 = *(const float4*)(xp + 32);
    float4 x11 = *(const float4*)(xp + 36);
    const float* scb = scale + b * CC + g * 8;
    const float* sfb = shift + b * CC + g * 8;
    float4 s00 = *(const float4*)(scb);
    float4 s01 = *(const float4*)(scb + 4);
    float4 s10 = *(const float4*)(scb + 32);
    float4 s11 = *(const float4*)(scb + 36);
    float4 f00 = *(const float4*)(sfb);
    float4 f01 = *(const float4*)(sfb + 4);
    float4 f10 = *(const float4*)(sfb + 32);
    float4 f11 = *(const float4*)(sfb + 36);

    union { bf16x8 v; unsigned u[4]; } af0, af1;
    af0.u[0] = packbf(x00.x * s00.x + f00.x, x00.y * s00.y + f00.y);
    af0.u[1] = packbf(x00.z * s00.z + f00.z, x00.w * s00.w + f00.w);
    af0.u[2] = packbf(x01.x * s01.x + f01.x, x01.y * s01.y + f01.y);
    af0.u[3] = packbf(x01.z * s01.z + f01.z, x01.w * s01.w + f01.w);
    af1.u[0] = packbf(x10.x * s10.x + f10.x, x10.y * s10.y + f10.y);
    af1.u[1] = packbf(x10.z * s10.z + f10.z, x10.w * s10.w + f10.w);
    af1.u[2] = packbf(x11.x * s11.x + f11.x, x11.y * s11.y + f11.y);
    af1.u[3] = packbf(x11.z * s11.z + f11.z, x11.w * s11.w + f11.w);

    #pragma unroll
    for (int m = 0; m < 3; ++m) {
        const float* bias = (m == 0) ? bq : (m == 1) ? bk : bv;
        #pragma unroll
        for (int dt = 0; dt < 4; ++dt) {
            bf16x8 w0 = *(const bf16x8*)(wfrag + (size_t)(((m * 4 + dt) * 2 + 0) * 64 + lane) * 8);
            bf16x8 w1 = *(const bf16x8*)(wfrag + (size_t)(((m * 4 + dt) * 2 + 1) * 64 + lane) * 8);
            f32x4 z = (f32x4){0.f, 0.f, 0.f, 0.f};
            z = __builtin_amdgcn_mfma_f32_16x16x32_bf16(af0.v, w0, z, 0, 0, 0);
            z = __builtin_amdgcn_mfma_f32_16x16x32_bf16(af1.v, w1, z, 0, 0, 0);
            float bias_d = bias[dt * 16 + cl];
            if (m == 0) {
                #pragma unroll
                for (int r = 0; r < 4; ++r)
                    qb[(size_t)(pix0 + 4 * g + r) * CC + dt * 16 + cl] =
                        (short)bf16bits((z[r] + bias_d) * 0.125f);
            } else if (m == 1) {
                #pragma unroll
                for (int r = 0; r < 4; ++r)
                    kb[(size_t)(pix0 + 4 * g + r) * CC + dt * 16 + cl] =
                        (short)bf16bits(z[r] + bias_d);
            } else {
                #pragma unroll
                for (int r = 0; r < 4; ++r)
                    vtile[(dt * 16 + cl) * 72 + wid * 16 + 4 * g + r] =
                        bf16bits(z[r] + bias_d);
            }
        }
    }
    __syncthreads();
    {
        int d = t >> 2, seg = t & 3;
        uint4 v0 = *(const uint4*)(vtile + d * 72 + seg * 16);
        uint4 v1 = *(const uint4*)(vtile + d * 72 + seg * 16 + 8);
        uint4* dst = (uint4*)(vt + ((size_t)(b * 64 + d)) * NN + pixblk + seg * 16);
        dst[0] = v0; dst[1] = v1;
    }
}

// ---------------- Kernel 4: flash attention, 32x32 MFMA, fixed-max -------
// grid = 128 qblocks * KSPLIT; block = 4 waves; wave = 32 queries, 512 keys.
__global__ __launch_bounds__(256, 2) void attn_mfma32(
        const short* __restrict__ qb, const short* __restrict__ kb,
        const short* __restrict__ vt,
        short* __restrict__ obf, float* __restrict__ msb) {
    const int lane = threadIdx.x & 63;
    const int wid  = threadIdx.x >> 6;
    const int hi  = lane >> 5;
    const int l31 = lane & 31;
    const int kseg   = blockIdx.x & (KSPLIT - 1);
    const int qblock = blockIdx.x >> 3;
    const int qtile  = qblock * 4 + wid;           // 0..511
    const int b = qtile >> 7;                      // 128 qtiles per batch
    const int key0 = kseg * (NN / KSPLIT);         // within batch

    // Q B-fragments: B[k=ch][col=q] ; lane: q=l31, ch=16s+8hi+j
    bf16x8 qf[4];
    const short* qp = qb + (size_t)(qtile * QBLK + l31) * CC + 8 * hi;
    #pragma unroll
    for (int s = 0; s < 4; ++s) qf[s] = *(const bf16x8*)(qp + 16 * s);

    const short* kptr = kb + ((size_t)b * NN + key0 + l31) * CC + 8 * hi;
    const short* vptr = vt + ((size_t)b * CC + l31) * NN + key0 + 8 * hi;

    f32x16 oacc0, oacc1;
    #pragma unroll
    for (int r = 0; r < 16; ++r) { oacc0[r] = 0.f; oacc1[r] = 0.f; }
    float psum = 0.f;

    bf16x8 kA[4], vA[4], kB[4], vB[4];

    auto loadc = [&](bf16x8 (&kf)[4], bf16x8 (&vf)[4], int c) {
        #pragma unroll
        for (int s = 0; s < 4; ++s)
            kf[s] = *(const bf16x8*)(kptr + (size_t)c * 32 * CC + 16 * s);
        vf[0] = *(const bf16x8*)(vptr + c * 32);            // ks0 dt0
        vf[1] = *(const bf16x8*)(vptr + 32 * NN + c * 32);  // ks0 dt1
        vf[2] = *(const bf16x8*)(vptr + c * 32 + 16);       // ks1 dt0
        vf[3] = *(const bf16x8*)(vptr + 32 * NN + c * 32 + 16);
    };

    auto body = [&](const bf16x8 (&kf)[4], const bf16x8 (&vf)[4]) {
        f32x16 st;
        #pragma unroll
        for (int r = 0; r < 16; ++r) st[r] = 0.f;
        #pragma unroll
        for (int s = 0; s < 4; ++s)
            st = __builtin_amdgcn_mfma_f32_32x32x16_bf16(kf[s], qf[s], st, 0, 0, 0);
        // lane-local softmax numerators (fixed max = 0); all 16 belong to query l31
        float p[16];
        float ps = 0.f;
        #pragma unroll
        for (int r = 0; r < 16; ++r) { p[r] = __expf(st[r]); ps += p[r]; }
        psum += ps;
        unsigned w[8];
        #pragma unroll
        for (int i = 0; i < 8; ++i) w[i] = cvtpk(p[2 * i], p[2 * i + 1]);
        // build PV A-fragments: PA0 = keys 8hi+0..7, PA1 = keys 16+8hi+0..7
        PSWAP(w[0], w[2]); PSWAP(w[1], w[3]);
        PSWAP(w[4], w[6]); PSWAP(w[5], w[7]);
        union { bf16x8 v; unsigned u[4]; } pa0, pa1;
        pa0.u[0] = w[0]; pa0.u[1] = w[1]; pa0.u[2] = w[2]; pa0.u[3] = w[3];
        pa1.u[0] = w[4]; pa1.u[1] = w[5]; pa1.u[2] = w[6]; pa1.u[3] = w[7];
        oacc0 = __builtin_amdgcn_mfma_f32_32x32x16_bf16(pa0.v, vf[0], oacc0, 0, 0, 0);
        oacc1 = __builtin_amdgcn_mfma_f32_32x32x16_bf16(pa0.v, vf[1], oacc1, 0, 0, 0);
        oacc0 = __builtin_amdgcn_mfma_f32_32x32x16_bf16(pa1.v, vf[2], oacc0, 0, 0, 0);
        oacc1 = __builtin_amdgcn_mfma_f32_32x32x16_bf16(pa1.v, vf[3], oacc1, 0, 0, 0);
    };

    loadc(kA, vA, 0);
    #pragma unroll 1
    for (int c = 0; c < 16; c += 2) {
        loadc(kB, vB, c + 1);
        body(kA, vA);
        if (c + 2 < 16) loadc(kA, vA, c + 2);
        body(kB, vB);
    }

    // store partial O (bf16) + per-lane partial row sums
    int task = qtile * KSPLIT + kseg;
    short* ob = obf + (size_t)task * (QBLK * CC);
    #pragma unroll
    for (int r = 0; r < 16; ++r) {
        int row = (r & 3) + 8 * (r >> 2) + 4 * hi;
        ob[row * CC + l31]      = (short)bf16bits(oacc0[r]);
        ob[row * CC + 32 + l31] = (short)bf16bits(oacc1[r]);
    }
    msb[task * 64 + lane] = psum;
}

// ---------------- Kernel 5: merge partials + out-proj + residual ---------
// grid 128, block 256 (4 waves). Wave handles one 32-query tile.
__global__ __launch_bounds__(256) void attn_merge_outproj(
        const short* __restrict__ obf, const float* __restrict__ msb,
        const short* __restrict__ wfrag,
        const float* __restrict__ x,
        const float* __restrict__ bo,
        float* __restrict__ out) {
    int t = threadIdx.x;
    int lane = t & 63, wid = t >> 6;
    int hi = lane >> 5, l31 = lane & 31;
    int qtile = blockIdx.x * 4 + wid;

    // total denominator for query l31
    float stot = 0.f;
    #pragma unroll
    for (int s = 0; s < KSPLIT; ++s) {
        stot += msb[(qtile * KSPLIT + s) * 64 + l31]
              + msb[(qtile * KSPLIT + s) * 64 + 32 + l31];
    }
    float inv = 1.f / stot;

    // accumulate O in A-fragment layout: lane: O[q=l31][ch=16s+8hi+j]
    float oa[4][8];
    #pragma unroll
    for (int s = 0; s < 4; ++s)
        #pragma unroll
        for (int j = 0; j < 8; ++j) oa[s][j] = 0.f;
    #pragma unroll
    for (int ks = 0; ks < KSPLIT; ++ks) {
        const short* base = obf + (size_t)(qtile * KSPLIT + ks) * (QBLK * CC)
                          + l31 * CC + 8 * hi;
        #pragma unroll
        for (int s = 0; s < 4; ++s) {
            bf16x8 v = *(const bf16x8*)(base + 16 * s);
            #pragma unroll
            for (int j = 0; j < 8; ++j) oa[s][j] += bf2f((unsigned short)v[j]);
        }
    }
    union { bf16x8 v; unsigned u[4]; } af[4];
    #pragma unroll
    for (int s = 0; s < 4; ++s)
        #pragma unroll
        for (int m = 0; m < 4; ++m)
            af[s].u[m] = packbf(oa[s][2 * m] * inv, oa[s][2 * m + 1] * inv);

    // out-proj: D[q][d] = O . Wo  (32x32 fragments)
    const short* w32 = wfrag + 12288;
    f32x16 z0, z1;
    #pragma unroll
    for (int r = 0; r < 16; ++r) { z0[r] = 0.f; z1[r] = 0.f; }
    #pragma unroll
    for (int s = 0; s < 4; ++s) {
        bf16x8 wb0 = *(const bf16x8*)(w32 + (size_t)((s * 2 + 0) * 64 + lane) * 8);
        bf16x8 wb1 = *(const bf16x8*)(w32 + (size_t)((s * 2 + 1) * 64 + lane) * 8);
        z0 = __builtin_amdgcn_mfma_f32_32x32x16_bf16(af[s].v, wb0, z0, 0, 0, 0);
        z1 = __builtin_amdgcn_mfma_f32_32x32x16_bf16(af[s].v, wb1, z1, 0, 0, 0);
    }
    float bo0 = bo[l31], bo1 = bo[32 + l31];
    #pragma unroll
    for (int r = 0; r < 16; ++r) {
        int row = (r & 3) + 8 * (r >> 2) + 4 * hi;
        size_t i0 = (size_t)(qtile * QBLK + row) * CC + l31;
        out[i0]      = x[i0]      + z0[r] + bo0;
        out[i0 + 32] = x[i0 + 32] + z1[r] + bo1;
    }
}

extern "C" void kernel_launch(void* const* d_in, const int* in_sizes, int n_in,
                              void* d_out, int out_size, void* d_ws, size_t ws_size,
                              hipStream_t stream) {
    const float* x     = (const float*)d_in[0];
    const float* gamma = (const float*)d_in[1];
    const float* beta  = (const float*)d_in[2];
    const float* wq    = (const float*)d_in[3];
    const float* bq    = (const float*)d_in[4];
    const float* wk    = (const float*)d_in[5];
    const float* bk    = (const float*)d_in[6];
    const float* wv    = (const float*)d_in[7];
    const float* bv    = (const float*)d_in[8];
    const float* wo    = (const float*)d_in[9];
    const float* bo    = (const float*)d_in[10];
    float* out = (float*)d_out;

    float* ws    = (float*)d_ws;
    float* scale = ws;                                   // 256
    float* shift = scale + 256;                          // 256
    float* part  = shift + 256;                          // 32768
    short* wfrag = (short*)(part + 32768);               // 16384 bf16
    short* qb    = wfrag + 16384;
    short* kbp   = qb  + (size_t)NPIX * CC;
    short* vtp   = kbp + (size_t)NPIX * CC;
    short* obf   = vtp + (size_t)NPIX * CC;              // 512*8*2048 bf16
    float* msb   = (float*)(obf + (size_t)NQT32 * KSPLIT * QBLK * CC);  // 512*8*64

    hipLaunchKernelGGL(wt_prep, dim3(16), dim3(256), 0, stream,
                       wq, wk, wv, wo, wfrag);
    hipLaunchKernelGGL(gn_partial, dim3(256), dim3(256), 0, stream, x, part);
    hipLaunchKernelGGL(gn_final, dim3(BB), dim3(256), 0, stream,
                       part, gamma, beta, scale, shift);
    hipLaunchKernelGGL(qkv_proj, dim3(256), dim3(256), 0, stream,
                       x, scale, shift, wfrag, bq, bk, bv, qb, kbp, vtp);
    hipLaunchKernelGGL(attn_mfma32, dim3((NPIX / 128) * KSPLIT), dim3(256), 0, stream,
                       qb, kbp, vtp, obf, msb);
    hipLaunchKernelGGL(attn_merge_outproj, dim3(NQT32 / 4), dim3(256), 0, stream,
                       obf, msb, wfrag, x, bo, out);
}